// Round 1
// 126.655 us; speedup vs baseline: 1.0632x; 1.0632x over previous
//
#include <hip/hip_runtime.h>
#include <cmath>

// CapsuleLayer routing, B=64, Ni=2048, Di=16, No=32, Do=16 (fp32 in/out).
// R5: FUSED plan — routing folded into the main MFMA kernel using the
// identity h[b,n,o] = sum_d hat[b,n,o,d] (row-sum of the MFMA output).
//  k_fused: per n: stage W/x (split-bf16) -> MFMA (D retained in regs) ->
//           h = row-sum(D) -> in-block 2-round softmax -> sacc += c2*D.
//           Block split by b-HALF (not o-half) so softmax over all 32 o is
//           block-local. XCD-paired blockIdx swizzle so the two b-half
//           blocks of one n-group share W through the same XCD's L2.
//           W is now read ONCE from HBM (was twice), c2g buffer eliminated.
//  k_reduce: unchanged (proven) — partial layout identical to R4.

#define NI 2048

typedef short bf16x8 __attribute__((ext_vector_type(8)));
typedef float f32x4 __attribute__((ext_vector_type(4)));

static __device__ __forceinline__ unsigned short f2bf(float f) {
  unsigned u = __float_as_uint(f);
  u += 0x7FFFu + ((u >> 16) & 1u);
  return (unsigned short)(u >> 16);
}
static __device__ __forceinline__ float bf2f(unsigned short h) {
  return __uint_as_float(((unsigned)h) << 16);
}
static __device__ __forceinline__ void split4(float4 v, uint2& hi, uint2& lo) {
  unsigned short h0 = f2bf(v.x), h1 = f2bf(v.y), h2 = f2bf(v.z), h3 = f2bf(v.w);
  unsigned short l0 = f2bf(v.x - bf2f(h0)), l1 = f2bf(v.y - bf2f(h1));
  unsigned short l2 = f2bf(v.z - bf2f(h2)), l3 = f2bf(v.w - bf2f(h3));
  hi.x = (unsigned)h0 | ((unsigned)h1 << 16); hi.y = (unsigned)h2 | ((unsigned)h3 << 16);
  lo.x = (unsigned)l0 | ((unsigned)l1 << 16); lo.y = (unsigned)l2 | ((unsigned)l3 << 16);
}

// ---------------- Fused kernel: MFMA + in-block routing + weighted accumulate ----
// grid 512; swizzle: xcd = bx&7, slot = bx>>3; ng = xcd*32 + slot/2, bh = slot&1
// (pairs (ng,0),(ng,1) land on the same XCD, 8 dispatch slots apart -> W L2-shared)
// block 512 = 8 waves = (bt = wv&1 b-tile of 16) x (oq = wv>>1 o-quarter of 8).
// A = [W_hi|W_lo] (m=d, K=32 packed split), B = [x_hi],[x_lo] dup along K.
// LDS dword offsets:
#define WAOFF 0        // 32 o * 32 rows (s*16+d) * 12 dwords = 12288
#define XBOFF 12288    // 64 rows (s*32+b_local) * 12 = 768
#define HOFF  13056    // h[b_local][o]: 32 * 33 = 1056
#define C2OFF 14112    // c2[o][b_local]: 32 * 33 = 1056
#define LDSZ  15168    // 60.7 KB -> 2 blocks/CU LDS-wise
__global__ __launch_bounds__(512, 4) void caps_fused_kernel(
    const float* __restrict__ x, const float* __restrict__ W,
    float* __restrict__ partial)
{
  const int bx = blockIdx.x;
  const int xcd = bx & 7, slot = bx >> 3;
  const int ng = xcd * 32 + (slot >> 1);
  const int bh = slot & 1;
  const int t = threadIdx.x;
  const int wv = t >> 6, l = t & 63;
  const int q = l >> 4, dq = l & 15, qh = q & 1, s_a = q >> 1;
  const int bt = wv & 1, oq = wv >> 1;

  __shared__ __align__(16) float lds[LDSZ];
  float* WA  = lds + WAOFF;
  float* XB  = lds + XBOFF;
  float* hS  = lds + HOFF;
  float* c2S = lds + C2OFF;

  float sacc[8][4];
  #pragma unroll
  for (int oo = 0; oo < 8; ++oo)
    { sacc[oo][0] = 0.f; sacc[oo][1] = 0.f; sacc[oo][2] = 0.f; sacc[oo][3] = 0.f; }

  const int n0 = ng * 8;
  // staging decompositions
  const int wo0 = t >> 6, wd = (t >> 2) & 15, wi4 = t & 3;  // W: o-chunk base, d, i4
  const int xb = t >> 2, xi4 = t & 3;                       // x: b_local, i4 (t<128)

  // initial global loads (full W[n]: 4 chunks of 8 o's)
  float4 wreg[4];
  #pragma unroll
  for (int c = 0; c < 4; ++c)
    wreg[c] = *(const float4*)(W + (size_t)n0 * 8192 + c * 2048 + 4 * t);
  float4 xreg = make_float4(0.f, 0.f, 0.f, 0.f);
  if (t < 128)
    xreg = *(const float4*)(x + (size_t)(bh * 32 + xb) * (NI * 16) + n0 * 16 + xi4 * 4);

  #pragma unroll 1
  for (int nn = 0; nn < 8; ++nn) {
    // ---- stage: split to bf16 and write LDS ----
    #pragma unroll
    for (int c = 0; c < 4; ++c) {
      uint2 hi, lo;
      split4(wreg[c], hi, lo);
      const int row = ((c * 8 + wo0) * 32 + wd) * 12;
      *(uint2*)((char*)&WA[row] + wi4 * 8) = hi;
      *(uint2*)((char*)&WA[row + 192] + wi4 * 8) = lo;   // +16 rows * 12
    }
    if (t < 128) {
      uint2 hi, lo;
      split4(xreg, hi, lo);
      *(uint2*)((char*)&XB[xb * 12] + xi4 * 8) = hi;
      *(uint2*)((char*)&XB[(32 + xb) * 12] + xi4 * 8) = lo;
    }
    __syncthreads();   // sync1: LDS staged

    // ---- prefetch next n (overlaps MFMA + routing below) ----
    if (nn < 7) {
      const size_t nb = (size_t)(n0 + nn + 1);
      #pragma unroll
      for (int c = 0; c < 4; ++c)
        wreg[c] = *(const float4*)(W + nb * 8192 + c * 2048 + 4 * t);
      if (t < 128)
        xreg = *(const float4*)(x + (size_t)(bh * 32 + xb) * (NI * 16) + nb * 16 + xi4 * 4);
    }

    // ---- MFMA: D retained per o; h = row-sum(D) -> LDS ----
    f32x4 Dv[8];
    {
      bf16x8 B0 = *(const bf16x8*)&XB[(bt * 16 + dq) * 12 + qh * 4];        // x_hi
      bf16x8 B1 = *(const bf16x8*)&XB[(32 + bt * 16 + dq) * 12 + qh * 4];   // x_lo
      #pragma unroll
      for (int oo = 0; oo < 8; ++oo) {
        const int o = oq * 8 + oo;
        bf16x8 A = *(const bf16x8*)&WA[(o * 32 + s_a * 16 + dq) * 12 + qh * 4];
        f32x4 D = {0.f, 0.f, 0.f, 0.f};
        D = __builtin_amdgcn_mfma_f32_16x16x32_bf16(A, B0, D, 0, 0, 0);
        D = __builtin_amdgcn_mfma_f32_16x16x32_bf16(A, B1, D, 0, 0, 0);
        Dv[oo] = D;
        // h[b,o] = sum_d hat: sum regs (rows q*4+r) then reduce over q
        float hs = D[0] + D[1] + D[2] + D[3];
        hs += __shfl_xor(hs, 16);
        hs += __shfl_xor(hs, 32);
        if (q == 0) hS[(bt * 16 + dq) * 33 + o] = hs;
      }
    }
    __syncthreads();   // sync2: h complete

    // ---- routing (R1-proven math): thread (b_local = t>>4, op = t&15),
    //      handles o = op and op+16; softmax reduce via 16-lane shuffles ----
    {
      const int bl = t >> 4, op = t & 15;
      const float h0 = hS[bl * 33 + op];
      const float h1 = hS[bl * 33 + op + 16];
      const float b10 = h0 * 0.03125f, b11 = h1 * 0.03125f;
      float mx = fmaxf(b10, b11);
      mx = fmaxf(mx, __shfl_xor(mx, 1)); mx = fmaxf(mx, __shfl_xor(mx, 2));
      mx = fmaxf(mx, __shfl_xor(mx, 4)); mx = fmaxf(mx, __shfl_xor(mx, 8));
      const float e0 = __expf(b10 - mx), e1 = __expf(b11 - mx);
      float S = e0 + e1;
      S += __shfl_xor(S, 1); S += __shfl_xor(S, 2);
      S += __shfl_xor(S, 4); S += __shfl_xor(S, 8);
      const float inv = 1.0f / S;
      const float b20 = b10 + e0 * inv * h0, b21 = b11 + e1 * inv * h1;
      float mx2 = fmaxf(b20, b21);
      mx2 = fmaxf(mx2, __shfl_xor(mx2, 1)); mx2 = fmaxf(mx2, __shfl_xor(mx2, 2));
      mx2 = fmaxf(mx2, __shfl_xor(mx2, 4)); mx2 = fmaxf(mx2, __shfl_xor(mx2, 8));
      const float e20 = __expf(b20 - mx2), e21 = __expf(b21 - mx2);
      float S2 = e20 + e21;
      S2 += __shfl_xor(S2, 1); S2 += __shfl_xor(S2, 2);
      S2 += __shfl_xor(S2, 4); S2 += __shfl_xor(S2, 8);
      const float inv2 = 1.0f / S2;
      c2S[op * 33 + bl] = e20 * inv2;
      c2S[(op + 16) * 33 + bl] = e21 * inv2;
    }
    __syncthreads();   // sync3: c2 ready

    // ---- weighted accumulate from retained D (no second MFMA pass) ----
    #pragma unroll
    for (int oo = 0; oo < 8; ++oo) {
      const int o = oq * 8 + oo;
      const float c = c2S[o * 33 + bt * 16 + dq];
      sacc[oo][0] += c * Dv[oo][0]; sacc[oo][1] += c * Dv[oo][1];
      sacc[oo][2] += c * Dv[oo][2]; sacc[oo][3] += c * Dv[oo][3];
    }
    // no sync needed: next stage writes WA/XB (last read before sync2),
    // weight reads c2S (next written only after next sync2)
  }

  // ---- epilogue: gidx-major, block-contiguous (proven clean-WRITE layout) ----
  // partial[ng][b_global][cell], cell = o*16 + d, d = q*4 + r
  float* pb = partial + (size_t)ng * 32768
            + (size_t)(bh * 32 + bt * 16 + dq) * 512 + q * 4;
  #pragma unroll
  for (int oo = 0; oo < 8; ++oo) {
    const int o = oq * 8 + oo;
    *(float4*)(pb + o * 16)
        = make_float4(sacc[oo][0], sacc[oo][1], sacc[oo][2], sacc[oo][3]);
  }
}

// ---------------- Kernel 2: reduce 256 group-partials + squash (unchanged) ----
__global__ __launch_bounds__(256) void caps_reduce_kernel(
    const float* __restrict__ partial, float* __restrict__ out)
{
  const int t = threadIdx.x;
  const int w4 = t >> 6, ln = t & 63;
  const int pair = blockIdx.x * 4 + w4;     // (b,o), 2048 total
  const int b = pair >> 5, o = pair & 31;
  const int d = ln & 15, cg = ln >> 4;
  const float* p = partial + (size_t)b * 512 + o * 16 + d;
  float s = 0.f;
  #pragma unroll 8
  for (int gg = cg; gg < 256; gg += 4) s += p[(size_t)gg * 32768];
  s += __shfl_xor(s, 16); s += __shfl_xor(s, 32);    // over cg
  float s2 = s * s;
  s2 += __shfl_xor(s2, 1); s2 += __shfl_xor(s2, 2);
  s2 += __shfl_xor(s2, 4); s2 += __shfl_xor(s2, 8);  // over d
  float scale = s2 / (1.0f + s2) / sqrtf(s2 + 1e-7f);
  if (ln < 16) out[(size_t)b * 512 + o * 16 + d] = scale * s;
}

extern "C" void kernel_launch(void* const* d_in, const int* in_sizes, int n_in,
                              void* d_out, int out_size, void* d_ws, size_t ws_size,
                              hipStream_t stream) {
  const float* x = (const float*)d_in[0];   // [64,2048,16]
  const float* W = (const float*)d_in[1];   // [1,2048,32,16,16]
  if (in_sizes[0] != 64 * 2048 * 16) { const float* tmp = x; x = W; W = tmp; }
  float* out = (float*)d_out;               // [64,32,16]

  float* partial = (float*)d_ws;            // 256*32768 f32 = 32 MB (gidx-major)

  caps_fused_kernel<<<512, 512, 0, stream>>>(x, W, partial);
  caps_reduce_kernel<<<512, 256, 0, stream>>>(partial, out);
}